// Round 1
// baseline (429.121 us; speedup 1.0000x reference)
//
#include <hip/hip_runtime.h>

#define T_LEN 1024
#define NH 8
#define DH 64
#define CCH 512

// ---------------------------------------------------------------------------
// Generic 1x1-conv projection GEMM: out[b,o,t] = scale*( sum_c W[o,c]*x[b,c,t] + bias[o] )
// 64x64 output tile per block, BK=16, 4x4 micro-tile per thread, 256 threads.
// ---------------------------------------------------------------------------
__global__ __launch_bounds__(256)
void proj_kernel(const float* __restrict__ x, const float* __restrict__ W,
                 const float* __restrict__ bias, float* __restrict__ out, float scale)
{
    const int t0  = blockIdx.x * 64;
    const int o0  = blockIdx.y * 64;
    const int b   = blockIdx.z;
    const int tid = threadIdx.x;

    __shared__ __align__(16) float As[16 * 68];   // [kc][o]
    __shared__ __align__(16) float Bs[16 * 68];   // [kc][t]

    const int la_o = tid >> 2;           // 0..63
    const int la_c = (tid & 3) * 4;      // 0,4,8,12
    const int lb_c = tid >> 4;           // 0..15
    const int lb_t = (tid & 15) * 4;     // 0..60

    const int rm = tid >> 4;             // o rows 4*rm
    const int tn = tid & 15;             // t cols 4*tn (fastest in tid -> coalesced stores)

    const float* xb = x + (size_t)b * CCH * T_LEN;

    float acc[4][4] = {};

    for (int c0 = 0; c0 < CCH; c0 += 16) {
        float4 a4 = *(const float4*)&W[(size_t)(o0 + la_o) * CCH + c0 + la_c];
        float4 b4 = *(const float4*)&xb[(size_t)(c0 + lb_c) * T_LEN + t0 + lb_t];
        As[(la_c + 0) * 68 + la_o] = a4.x;
        As[(la_c + 1) * 68 + la_o] = a4.y;
        As[(la_c + 2) * 68 + la_o] = a4.z;
        As[(la_c + 3) * 68 + la_o] = a4.w;
        *(float4*)&Bs[lb_c * 68 + lb_t] = b4;
        __syncthreads();
        #pragma unroll
        for (int kc = 0; kc < 16; ++kc) {
            float4 av = *(const float4*)&As[kc * 68 + 4 * rm];
            float4 bv = *(const float4*)&Bs[kc * 68 + 4 * tn];
            float aa[4] = {av.x, av.y, av.z, av.w};
            float bb[4] = {bv.x, bv.y, bv.z, bv.w};
            #pragma unroll
            for (int i = 0; i < 4; ++i)
                #pragma unroll
                for (int j = 0; j < 4; ++j)
                    acc[i][j] += aa[i] * bb[j];
        }
        __syncthreads();
    }

    float* ob = out + (size_t)b * CCH * T_LEN;
    #pragma unroll
    for (int i = 0; i < 4; ++i) {
        float bv = bias[o0 + 4 * rm + i];
        float4 w;
        w.x = (acc[i][0] + bv) * scale;
        w.y = (acc[i][1] + bv) * scale;
        w.z = (acc[i][2] + bv) * scale;
        w.w = (acc[i][3] + bv) * scale;
        *(float4*)&ob[(size_t)(o0 + 4 * rm + i) * T_LEN + t0 + 4 * tn] = w;
    }
}

// ---------------------------------------------------------------------------
// Flash attention with this reference's (non-standard!) relative-K bias and
// standard relative-V term. One block per (b, h, 64-query tile). 256 threads.
//
// Derived semantics (front-padded _relative_to_absolute):
//   scores[t,s] += dot(q[t],   emb_k[s-t-1019])   if s-t in [1019,1023]
//   scores[t,s] += dot(q[t-1], emb_k[1029-(t-s)]) if t-s in [1021,1023]
// rel-V (standard): ctx[t] += sum_{|s-t|<=4} attn[t,s] * emb_v[s-t+4]
// ---------------------------------------------------------------------------
__global__ __launch_bounds__(256)
void attn_kernel(const float* __restrict__ q, const float* __restrict__ k,
                 const float* __restrict__ v, const float* __restrict__ ek_g,
                 const float* __restrict__ ev_g, float* __restrict__ ctx)
{
    const int t0  = blockIdx.x * 64;
    const int h   = blockIdx.y;
    const int b   = blockIdx.z;
    const int tid = threadIdx.x;

    __shared__ __align__(16) float Qs[64 * 68];   // [d][r]
    __shared__ __align__(16) float Ks[64 * 68];   // [d][s]
    __shared__ __align__(16) float Vs[64 * 68];   // [s][d]
    __shared__ __align__(16) float Ps[64 * 68];   // [s][r]
    __shared__ __align__(16) float red[16 * 64];  // [sn][row] partial max/sum
    __shared__ float mrow[64], lrow[64], arow[64];
    __shared__ __align__(16) float ek[9 * 64];
    __shared__ __align__(16) float ev[9 * 64];

    for (int idx = tid; idx < 9 * 64; idx += 256) {
        ek[idx] = ek_g[(size_t)h * 9 * 64 + idx];
        ev[idx] = ev_g[(size_t)h * 9 * 64 + idx];
    }
    if (tid < 64) { mrow[tid] = -1e30f; lrow[tid] = 0.f; }

    const size_t base = ((size_t)b * CCH + (size_t)h * DH) * T_LEN;

    const int ld_d = tid >> 2;          // 0..63
    const int ld_t = (tid & 3) * 16;    // 0,16,32,48

    // Q tile (loaded once): Qs[d][r]
    {
        const float* qrow = q + base + (size_t)ld_d * T_LEN + t0 + ld_t;
        #pragma unroll
        for (int kk = 0; kk < 4; ++kk)
            *(float4*)&Qs[ld_d * 68 + ld_t + 4 * kk] = *(const float4*)&qrow[4 * kk];
    }
    __syncthreads();

    const int rm = tid & 15;   // query rows 4*rm (fastest in tid)
    const int sn = tid >> 4;   // S cols / O d-cols 4*sn
    float O[4][4] = {};

    for (int kb = 0; kb < 16; ++kb) {
        const int s0 = kb * 64;
        __syncthreads();   // (1) prev iteration readers of Ks/Vs/Ps/red done

        // stage K (natural) and V (transposed) tiles
        {
            const float* krow = k + base + (size_t)ld_d * T_LEN + s0 + ld_t;
            const float* vrow = v + base + (size_t)ld_d * T_LEN + s0 + ld_t;
            #pragma unroll
            for (int kk = 0; kk < 4; ++kk) {
                *(float4*)&Ks[ld_d * 68 + ld_t + 4 * kk] = *(const float4*)&krow[4 * kk];
                float4 vv = *(const float4*)&vrow[4 * kk];
                Vs[(ld_t + 4 * kk + 0) * 68 + ld_d] = vv.x;
                Vs[(ld_t + 4 * kk + 1) * 68 + ld_d] = vv.y;
                Vs[(ld_t + 4 * kk + 2) * 68 + ld_d] = vv.z;
                Vs[(ld_t + 4 * kk + 3) * 68 + ld_d] = vv.w;
            }
        }
        __syncthreads();   // (2) tiles ready

        // ----- S = Q K^T micro-tile -----
        float S[4][4] = {};
        #pragma unroll 8
        for (int d = 0; d < 64; ++d) {
            float4 a  = *(const float4*)&Qs[d * 68 + 4 * rm];
            float4 bb = *(const float4*)&Ks[d * 68 + 4 * sn];
            float aa[4] = {a.x, a.y, a.z, a.w};
            float bv[4] = {bb.x, bb.y, bb.z, bb.w};
            #pragma unroll
            for (int i = 0; i < 4; ++i)
                #pragma unroll
                for (int j = 0; j < 4; ++j)
                    S[i][j] += aa[i] * bv[j];
        }

        // ----- corner relative-K bias (rare) -----
        const int db2 = (s0 + 4 * sn) - (t0 + 4 * rm);   // s - t at (i=0,j=0)
        if (db2 >= 1016 && db2 <= 1026) {
            #pragma unroll
            for (int i = 0; i < 4; ++i)
                #pragma unroll
                for (int j = 0; j < 4; ++j) {
                    int df = db2 + j - i;
                    if (df >= 1019 && df <= 1023) {
                        const float* ekp = &ek[(df - 1019) * 64];
                        const int row = 4 * rm + i;
                        float sacc = 0.f;
                        for (int dd = 0; dd < 64; ++dd) sacc += Qs[dd * 68 + row] * ekp[dd];
                        S[i][j] += sacc;
                    }
                }
        }
        if (db2 >= -1026 && db2 <= -1018) {
            #pragma unroll
            for (int i = 0; i < 4; ++i)
                #pragma unroll
                for (int j = 0; j < 4; ++j) {
                    int df = db2 + j - i;
                    if (df >= -1023 && df <= -1021) {
                        const float* ekp = &ek[(1029 + df) * 64];
                        const int row = 4 * rm + i - 1;   // uses q[t-1]; row>=60 whenever triggered
                        float sacc = 0.f;
                        for (int dd = 0; dd < 64; ++dd) sacc += Qs[dd * 68 + row] * ekp[dd];
                        S[i][j] += sacc;
                    }
                }
        }

        // partial row max
        #pragma unroll
        for (int i = 0; i < 4; ++i) {
            float pm = fmaxf(fmaxf(S[i][0], S[i][1]), fmaxf(S[i][2], S[i][3]));
            red[sn * 64 + 4 * rm + i] = pm;
        }
        __syncthreads();   // (3)

        if (tid < 64) {
            float m_t = red[tid];
            #pragma unroll
            for (int s2 = 1; s2 < 16; ++s2) m_t = fmaxf(m_t, red[s2 * 64 + tid]);
            float m_old = mrow[tid];
            float m_new = fmaxf(m_old, m_t);
            arow[tid] = __expf(m_old - m_new);
            mrow[tid] = m_new;
        }
        __syncthreads();   // (4)

        // p = exp(S - m_new); write Ps[s][r]; partial sums; rescale O
        float mi[4], al[4], rs[4] = {};
        #pragma unroll
        for (int i = 0; i < 4; ++i) { mi[i] = mrow[4 * rm + i]; al[i] = arow[4 * rm + i]; }
        #pragma unroll
        for (int i = 0; i < 4; ++i)
            #pragma unroll
            for (int j = 0; j < 4; ++j) {
                S[i][j] = __expf(S[i][j] - mi[i]);
                rs[i] += S[i][j];
            }
        #pragma unroll
        for (int j = 0; j < 4; ++j) {
            float4 w; w.x = S[0][j]; w.y = S[1][j]; w.z = S[2][j]; w.w = S[3][j];
            *(float4*)&Ps[(4 * sn + j) * 68 + 4 * rm] = w;
        }
        #pragma unroll
        for (int i = 0; i < 4; ++i) red[sn * 64 + 4 * rm + i] = rs[i];
        #pragma unroll
        for (int i = 0; i < 4; ++i)
            #pragma unroll
            for (int jd = 0; jd < 4; ++jd)
                O[i][jd] *= al[i];
        __syncthreads();   // (5)

        if (tid < 64) {
            float ssum = 0.f;
            #pragma unroll
            for (int s2 = 0; s2 < 16; ++s2) ssum += red[s2 * 64 + tid];
            lrow[tid] = lrow[tid] * arow[tid] + ssum;
        }

        // ----- O += P V micro-tile (+ windowed rel-V) -----
        const int dbase0 = s0 - (t0 + 4 * rm);
        #pragma unroll 4
        for (int s = 0; s < 64; ++s) {
            float4 a  = *(const float4*)&Ps[s * 68 + 4 * rm];
            float4 bb = *(const float4*)&Vs[s * 68 + 4 * sn];
            float aa[4] = {a.x, a.y, a.z, a.w};
            float bv[4] = {bb.x, bb.y, bb.z, bb.w};
            #pragma unroll
            for (int i = 0; i < 4; ++i)
                #pragma unroll
                for (int jd = 0; jd < 4; ++jd)
                    O[i][jd] += aa[i] * bv[jd];
            int dbase = dbase0 + s;
            if (dbase >= -4 && dbase <= 7) {
                #pragma unroll
                for (int i = 0; i < 4; ++i) {
                    int df = dbase - i;
                    if (df >= -4 && df <= 4) {
                        const float* evp = &ev[(df + 4) * 64 + 4 * sn];
                        #pragma unroll
                        for (int jd = 0; jd < 4; ++jd)
                            O[i][jd] += aa[i] * evp[jd];
                    }
                }
            }
        }
    }

    __syncthreads();   // lrow final values visible
    float li[4];
    #pragma unroll
    for (int i = 0; i < 4; ++i) li[i] = 1.0f / lrow[4 * rm + i];

    float* crow = ctx + base;
    #pragma unroll
    for (int jd = 0; jd < 4; ++jd) {
        float4 w;
        w.x = O[0][jd] * li[0];
        w.y = O[1][jd] * li[1];
        w.z = O[2][jd] * li[2];
        w.w = O[3][jd] * li[3];
        *(float4*)&crow[(size_t)(4 * sn + jd) * T_LEN + t0 + 4 * rm] = w;
    }
}

// ---------------------------------------------------------------------------
extern "C" void kernel_launch(void* const* d_in, const int* in_sizes, int n_in,
                              void* d_out, int out_size, void* d_ws, size_t ws_size,
                              hipStream_t stream)
{
    const float* x_q = (const float*)d_in[0];
    const float* x_k = (const float*)d_in[1];
    const float* x_v = (const float*)d_in[2];
    const float* Wq  = (const float*)d_in[3];
    const float* bq  = (const float*)d_in[4];
    const float* Wk  = (const float*)d_in[5];
    const float* bk  = (const float*)d_in[6];
    const float* Wv  = (const float*)d_in[7];
    const float* bv  = (const float*)d_in[8];
    const float* Wo  = (const float*)d_in[9];
    const float* bo  = (const float*)d_in[10];
    const float* erk = (const float*)d_in[11];
    const float* erv = (const float*)d_in[12];

    const int B = in_sizes[0] / (CCH * T_LEN);
    const size_t tensor_elems = (size_t)B * CCH * T_LEN;

    float* qw = (float*)d_ws;
    float* kw = qw + tensor_elems;
    float* vw = kw + tensor_elems;
    float* cw = vw + tensor_elems;

    dim3 blk(256);
    dim3 gproj(T_LEN / 64, CCH / 64, B);
    dim3 gattn(T_LEN / 64, NH, B);

    proj_kernel<<<gproj, blk, 0, stream>>>(x_q, Wq, bq, qw, 0.125f);  // 1/sqrt(64) folded
    proj_kernel<<<gproj, blk, 0, stream>>>(x_k, Wk, bk, kw, 1.0f);
    proj_kernel<<<gproj, blk, 0, stream>>>(x_v, Wv, bv, vw, 1.0f);
    attn_kernel<<<gattn, blk, 0, stream>>>(qw, kw, vw, erk, erv, cw);
    proj_kernel<<<gproj, blk, 0, stream>>>(cw, Wo, bo, (float*)d_out, 1.0f);
}

// Round 2
// 171.359 us; speedup vs baseline: 2.5042x; 2.5042x over previous
//
#include <hip/hip_runtime.h>

#define T_LEN 1024
#define NH 8
#define DH 64
#define CCH 512
#define LOG2E 1.44269504088896340736f

typedef _Float16 f16;
typedef _Float16 f16x8 __attribute__((ext_vector_type(8)));
typedef _Float16 f16x4 __attribute__((ext_vector_type(4)));
typedef float f32x4 __attribute__((ext_vector_type(4)));

// ---------------------------------------------------------------------------
// Transpose + fp32->fp16: x [b][c][t] -> xT [b*t][c]  (c contiguous)
// grid(T/64, C/64, 3*B), block 256
// ---------------------------------------------------------------------------
__global__ __launch_bounds__(256)
void xpose_fp16(const float* __restrict__ x0, const float* __restrict__ x1,
                const float* __restrict__ x2, f16* __restrict__ o0,
                f16* __restrict__ o1, f16* __restrict__ o2, int B)
{
    const int t0 = blockIdx.x * 64, c0 = blockIdx.y * 64;
    const int which = blockIdx.z / B, b = blockIdx.z % B;
    const float* x = (which == 0) ? x0 : (which == 1) ? x1 : x2;
    f16* o = (which == 0) ? o0 : (which == 1) ? o1 : o2;

    __shared__ float L[64 * 68];
    const int cl = threadIdx.x & 63, g = threadIdx.x >> 6;
    const float* src = x + ((size_t)(b * CCH + c0 + cl)) * T_LEN + t0 + g * 16;
    #pragma unroll
    for (int j = 0; j < 4; ++j)
        *(float4*)&L[cl * 68 + g * 16 + 4 * j] = *(const float4*)&src[4 * j];
    __syncthreads();
    const int tl = threadIdx.x & 63, cg = (threadIdx.x >> 6) * 16;
    f16 h[16];
    #pragma unroll
    for (int j = 0; j < 16; ++j) h[j] = (f16)L[(cg + j) * 68 + tl];
    f16* dst = o + ((size_t)(b * T_LEN + t0 + tl)) * CCH + c0 + cg;
    *(f16x8*)&dst[0] = *(f16x8*)&h[0];
    *(f16x8*)&dst[8] = *(f16x8*)&h[8];
}

// ---------------------------------------------------------------------------
// W fp32 -> fp16 (layout preserved, [o][c]). grid(256, 4), block 256
// ---------------------------------------------------------------------------
__global__ __launch_bounds__(256)
void wconv(const float* __restrict__ w0, const float* __restrict__ w1,
           const float* __restrict__ w2, const float* __restrict__ w3,
           f16* __restrict__ o0, f16* __restrict__ o1,
           f16* __restrict__ o2, f16* __restrict__ o3)
{
    const int y = blockIdx.y;
    const float* w = (y == 0) ? w0 : (y == 1) ? w1 : (y == 2) ? w2 : w3;
    f16* o = (y == 0) ? o0 : (y == 1) ? o1 : (y == 2) ? o2 : o3;
    const int i = (blockIdx.x * 256 + threadIdx.x) * 4;
    float4 v = *(const float4*)&w[i];
    f16x4 hv = {(f16)v.x, (f16)v.y, (f16)v.z, (f16)v.w};
    *(f16x4*)&o[i] = hv;
}

// ---------------------------------------------------------------------------
// Fused q/k/v projections, fp16 MFMA. grid(B*16, 8, 3), block 256.
// which=0,1 (q,k): D[m=t][n=o], store [b*t][c] fp16 (q scaled by 0.125*log2e)
// which=2   (v):   D[m=o][n=t], store [b][c][t] fp16
// ---------------------------------------------------------------------------
__global__ __launch_bounds__(256)
void proj_qkv(const f16* __restrict__ xq, const f16* __restrict__ xk,
              const f16* __restrict__ xv, const f16* __restrict__ wq,
              const f16* __restrict__ wk, const f16* __restrict__ wv,
              const float* __restrict__ bq, const float* __restrict__ bk,
              const float* __restrict__ bv, f16* __restrict__ qo,
              f16* __restrict__ ko, f16* __restrict__ vo)
{
    const int which = blockIdx.z;
    const f16* X = (which == 0) ? xq : (which == 1) ? xk : xv;
    const f16* W = (which == 0) ? wq : (which == 1) ? wk : wv;
    const float* bias = (which == 0) ? bq : (which == 1) ? bk : bv;
    const float scale = (which == 0) ? 0.125f * LOG2E : 1.0f;

    const int r0 = blockIdx.x * 64;   // flat (b,t) row
    const int o0 = blockIdx.y * 64;   // out channel
    const int tid = threadIdx.x;
    const int w = tid >> 6, quad = (tid >> 4) & 3, l15 = tid & 15;

    __shared__ f16 Xs[64 * 72], Ws[64 * 72];
    f32x4 acc[4] = {};

    for (int c0 = 0; c0 < CCH; c0 += 64) {
        if (c0) __syncthreads();
        #pragma unroll
        for (int j = 0; j < 2; ++j) {
            int cid = tid + 256 * j;
            int row = cid >> 3, c8 = (cid & 7) * 8;
            *(f16x8*)&Xs[row * 72 + c8] = *(const f16x8*)&X[(size_t)(r0 + row) * CCH + c0 + c8];
            *(f16x8*)&Ws[row * 72 + c8] = *(const f16x8*)&W[(size_t)(o0 + row) * CCH + c0 + c8];
        }
        __syncthreads();
        const f16* Ab = (which < 2) ? Xs : Ws;
        const f16* Bb = (which < 2) ? Ws : Xs;
        #pragma unroll
        for (int ks = 0; ks < 2; ++ks) {
            f16x8 a = *(const f16x8*)&Ab[(16 * w + l15) * 72 + ks * 32 + quad * 8];
            #pragma unroll
            for (int ct = 0; ct < 4; ++ct) {
                f16x8 bf = *(const f16x8*)&Bb[(16 * ct + l15) * 72 + ks * 32 + quad * 8];
                acc[ct] = __builtin_amdgcn_mfma_f32_16x16x32_f16(a, bf, acc[ct], 0, 0, 0);
            }
        }
    }

    if (which < 2) {
        f16* out = (which == 0) ? qo : ko;
        #pragma unroll
        for (int ct = 0; ct < 4; ++ct) {
            int col = o0 + 16 * ct + l15;
            float bvl = bias[col];
            #pragma unroll
            for (int r = 0; r < 4; ++r) {
                int row = r0 + 16 * w + quad * 4 + r;
                out[(size_t)row * CCH + col] = (f16)((acc[ct][r] + bvl) * scale);
            }
        }
    } else {
        const int bb = r0 >> 10, tb = r0 & 1023;
        #pragma unroll
        for (int r = 0; r < 4; ++r) {
            int row_o = o0 + 16 * w + quad * 4 + r;
            float bvl = bias[row_o];
            #pragma unroll
            for (int ct = 0; ct < 4; ++ct)
                vo[((size_t)(bb * CCH + row_o)) * T_LEN + tb + 16 * ct + l15] =
                    (f16)(acc[ct][r] + bvl);
        }
    }
}

// ---------------------------------------------------------------------------
// Output projection: out[b][o][t] fp32 = Wo * ctx + bo.
// A = Wo [o][c], B = ctx [b*t][c]. grid(B*16, 8), block 256.
// ---------------------------------------------------------------------------
__global__ __launch_bounds__(256)
void proj_out(const f16* __restrict__ ctx, const f16* __restrict__ Wo,
              const float* __restrict__ bo, float* __restrict__ out)
{
    const int r0 = blockIdx.x * 64;   // flat (b,t)
    const int o0 = blockIdx.y * 64;
    const int tid = threadIdx.x;
    const int w = tid >> 6, quad = (tid >> 4) & 3, l15 = tid & 15;

    __shared__ f16 Xs[64 * 72], Ws[64 * 72];
    f32x4 acc[4] = {};

    for (int c0 = 0; c0 < CCH; c0 += 64) {
        if (c0) __syncthreads();
        #pragma unroll
        for (int j = 0; j < 2; ++j) {
            int cid = tid + 256 * j;
            int row = cid >> 3, c8 = (cid & 7) * 8;
            *(f16x8*)&Xs[row * 72 + c8] = *(const f16x8*)&ctx[(size_t)(r0 + row) * CCH + c0 + c8];
            *(f16x8*)&Ws[row * 72 + c8] = *(const f16x8*)&Wo[(size_t)(o0 + row) * CCH + c0 + c8];
        }
        __syncthreads();
        #pragma unroll
        for (int ks = 0; ks < 2; ++ks) {
            f16x8 a = *(const f16x8*)&Ws[(16 * w + l15) * 72 + ks * 32 + quad * 8];
            #pragma unroll
            for (int ct = 0; ct < 4; ++ct) {
                f16x8 bf = *(const f16x8*)&Xs[(16 * ct + l15) * 72 + ks * 32 + quad * 8];
                acc[ct] = __builtin_amdgcn_mfma_f32_16x16x32_f16(a, bf, acc[ct], 0, 0, 0);
            }
        }
    }

    const int bb = r0 >> 10, tb = r0 & 1023;
    #pragma unroll
    for (int r = 0; r < 4; ++r) {
        int row_o = o0 + 16 * w + quad * 4 + r;
        float bvl = bo[row_o];
        #pragma unroll
        for (int ct = 0; ct < 4; ++ct)
            out[((size_t)(bb * CCH + row_o)) * T_LEN + tb + 16 * ct + l15] =
                acc[ct][r] + bvl;
    }
}

// ---------------------------------------------------------------------------
// MFMA flash attention. grid(16, NH, B), block 256 (4 waves).
// Wave w owns query rows 16w..16w+15 of the 64-row tile -> softmax state in
// registers, reductions via shfl_xor over the 16-lane column group.
// q,k in [b*t][c] fp16 (scaled q includes log2e); v in [b][c][t] fp16.
// Corner rel-K bias + windowed rel-V per round-1 verified semantics.
// ---------------------------------------------------------------------------
__global__ __launch_bounds__(256)
void attn_mfma(const f16* __restrict__ q, const f16* __restrict__ k,
               const f16* __restrict__ v, const float* __restrict__ ekg,
               const float* __restrict__ evg, f16* __restrict__ ctx)
{
    const int t0 = blockIdx.x * 64, h = blockIdx.y, b = blockIdx.z;
    const int tid = threadIdx.x;
    const int w = tid >> 6, quad = (tid >> 4) & 3, l15 = tid & 15;

    __shared__ f16 Qs[64 * 72], Ks[64 * 72], Vs[64 * 72], Ps[64 * 72];
    __shared__ float eks[9 * 64], evs[9 * 64];

    for (int i = tid; i < 9 * 64; i += 256) {
        eks[i] = ekg[h * 9 * 64 + i];
        evs[i] = evg[h * 9 * 64 + i];
    }
    #pragma unroll
    for (int j = 0; j < 2; ++j) {
        int cid = tid + 256 * j;
        int row = cid >> 3, c8 = (cid & 7) * 8;
        *(f16x8*)&Qs[row * 72 + c8] =
            *(const f16x8*)&q[((size_t)(b * T_LEN + t0 + row)) * CCH + h * DH + c8];
    }
    __syncthreads();

    float m_run[4], l_run[4];
    f32x4 O[4] = {};
    #pragma unroll
    for (int r = 0; r < 4; ++r) { m_run[r] = -1e30f; l_run[r] = 0.f; }

    const bool corner_hi = (blockIdx.x == 0);    // t small: bias at kb==15
    const bool corner_lo = (blockIdx.x == 15);   // t large: bias at kb==0

    for (int kb = 0; kb < 16; ++kb) {
        const int s0 = kb * 64;
        if (kb) __syncthreads();
        #pragma unroll
        for (int j = 0; j < 2; ++j) {
            int cid = tid + 256 * j;
            int row = cid >> 3, c8 = (cid & 7) * 8;
            *(f16x8*)&Ks[row * 72 + c8] =
                *(const f16x8*)&k[((size_t)(b * T_LEN + s0 + row)) * CCH + h * DH + c8];
            *(f16x8*)&Vs[row * 72 + c8] =
                *(const f16x8*)&v[((size_t)(b * CCH + h * DH + row)) * T_LEN + s0 + c8];
        }
        __syncthreads();

        // ----- S = Q K^T -----
        f32x4 S[4] = {};
        #pragma unroll
        for (int ks = 0; ks < 2; ++ks) {
            f16x8 a = *(const f16x8*)&Qs[(16 * w + l15) * 72 + ks * 32 + quad * 8];
            #pragma unroll
            for (int ct = 0; ct < 4; ++ct) {
                f16x8 bf = *(const f16x8*)&Ks[(16 * ct + l15) * 72 + ks * 32 + quad * 8];
                S[ct] = __builtin_amdgcn_mfma_f32_16x16x32_f16(a, bf, S[ct], 0, 0, 0);
            }
        }

        // ----- corner relative-K bias (rare; q already carries log2e) -----
        if ((corner_hi && kb == 15) || (corner_lo && kb == 0)) {
            #pragma unroll
            for (int ct = 0; ct < 4; ++ct)
                #pragma unroll
                for (int r = 0; r < 4; ++r) {
                    int row_l = 16 * w + quad * 4 + r;
                    int df = (s0 + 16 * ct + l15) - (t0 + row_l);
                    if (df >= 1019 && df <= 1023) {
                        const float* ekp = &eks[(df - 1019) * 64];
                        float sacc = 0.f;
                        for (int d = 0; d < 64; ++d)
                            sacc += (float)Qs[row_l * 72 + d] * ekp[d];
                        S[ct][r] += sacc;
                    } else if (df >= -1023 && df <= -1021) {
                        const float* ekp = &eks[(1029 + df) * 64];
                        float sacc = 0.f;
                        for (int d = 0; d < 64; ++d)
                            sacc += (float)Qs[(row_l - 1) * 72 + d] * ekp[d];
                        S[ct][r] += sacc;
                    }
                }
        }

        // ----- online softmax (log2 domain, per-wave rows) -----
        float alpha[4];
        #pragma unroll
        for (int r = 0; r < 4; ++r) {
            float m = fmaxf(fmaxf(S[0][r], S[1][r]), fmaxf(S[2][r], S[3][r]));
            #pragma unroll
            for (int d = 1; d < 16; d <<= 1) m = fmaxf(m, __shfl_xor(m, d));
            float mn = fmaxf(m_run[r], m);
            alpha[r] = exp2f(m_run[r] - mn);
            m_run[r] = mn;
        }
        #pragma unroll
        for (int r = 0; r < 4; ++r) {
            float p0 = exp2f(S[0][r] - m_run[r]);
            float p1 = exp2f(S[1][r] - m_run[r]);
            float p2 = exp2f(S[2][r] - m_run[r]);
            float p3 = exp2f(S[3][r] - m_run[r]);
            S[0][r] = p0; S[1][r] = p1; S[2][r] = p2; S[3][r] = p3;
            float rs = p0 + p1 + p2 + p3;
            #pragma unroll
            for (int d = 1; d < 16; d <<= 1) rs += __shfl_xor(rs, d);
            l_run[r] = l_run[r] * alpha[r] + rs;
            O[0][r] *= alpha[r]; O[1][r] *= alpha[r];
            O[2][r] *= alpha[r]; O[3][r] *= alpha[r];
        }

        // ----- P -> LDS (C-layout -> A-layout round trip) -----
        #pragma unroll
        for (int ct = 0; ct < 4; ++ct)
            #pragma unroll
            for (int r = 0; r < 4; ++r)
                Ps[(16 * w + quad * 4 + r) * 72 + 16 * ct + l15] = (f16)S[ct][r];
        __syncthreads();

        // ----- O += P V -----
        #pragma unroll
        for (int ks = 0; ks < 2; ++ks) {
            f16x8 a = *(const f16x8*)&Ps[(16 * w + l15) * 72 + ks * 32 + quad * 8];
            #pragma unroll
            for (int ct = 0; ct < 4; ++ct) {
                f16x8 bf = *(const f16x8*)&Vs[(16 * ct + l15) * 72 + ks * 32 + quad * 8];
                O[ct] = __builtin_amdgcn_mfma_f32_16x16x32_f16(a, bf, O[ct], 0, 0, 0);
            }
        }

        // ----- windowed relative-V -----
        if (s0 <= t0 + 67 && s0 + 63 >= t0 - 4) {
            #pragma unroll
            for (int r = 0; r < 4; ++r) {
                int row_l = 16 * w + quad * 4 + r;
                int t_g = t0 + row_l;
                int slo = max(s0, t_g - 4), shi = min(s0 + 63, t_g + 4);
                for (int s = slo; s <= shi; ++s) {
                    float p = (float)Ps[row_l * 72 + (s - s0)];
                    const float* evp = &evs[(s - t_g + 4) * 64];
                    #pragma unroll
                    for (int ct = 0; ct < 4; ++ct)
                        O[ct][r] += p * evp[16 * ct + l15];
                }
            }
        }
    }

    #pragma unroll
    for (int r = 0; r < 4; ++r) l_run[r] = 1.0f / l_run[r];
    #pragma unroll
    for (int ct = 0; ct < 4; ++ct)
        #pragma unroll
        for (int r = 0; r < 4; ++r) {
            int row = t0 + 16 * w + quad * 4 + r;
            ctx[((size_t)(b * T_LEN + row)) * CCH + h * DH + 16 * ct + l15] =
                (f16)(O[ct][r] * l_run[r]);
        }
}

// ---------------------------------------------------------------------------
extern "C" void kernel_launch(void* const* d_in, const int* in_sizes, int n_in,
                              void* d_out, int out_size, void* d_ws, size_t ws_size,
                              hipStream_t stream)
{
    const float* x_q = (const float*)d_in[0];
    const float* x_k = (const float*)d_in[1];
    const float* x_v = (const float*)d_in[2];
    const float* Wq  = (const float*)d_in[3];
    const float* bq  = (const float*)d_in[4];
    const float* Wk  = (const float*)d_in[5];
    const float* bk  = (const float*)d_in[6];
    const float* Wv  = (const float*)d_in[7];
    const float* bv  = (const float*)d_in[8];
    const float* Wo  = (const float*)d_in[9];
    const float* bo  = (const float*)d_in[10];
    const float* erk = (const float*)d_in[11];
    const float* erv = (const float*)d_in[12];

    const int B = in_sizes[0] / (CCH * T_LEN);
    const size_t te = (size_t)B * CCH * T_LEN;     // elements per tensor
    const size_t we = (size_t)CCH * CCH;

    f16* p = (f16*)d_ws;
    f16* xTq = p; p += te;
    f16* xTk = p; p += te;
    f16* xTv = p; p += te;
    f16* wqh = p; p += we;
    f16* wkh = p; p += we;
    f16* wvh = p; p += we;
    f16* woh = p; p += we;
    f16* qh  = p; p += te;
    f16* kh  = p; p += te;
    f16* vh  = p; p += te;
    f16* ch  = p; p += te;

    dim3 blk(256);
    xpose_fp16<<<dim3(T_LEN / 64, CCH / 64, 3 * B), blk, 0, stream>>>(
        x_q, x_k, x_v, xTq, xTk, xTv, B);
    wconv<<<dim3(256, 4), blk, 0, stream>>>(Wq, Wk, Wv, Wo, wqh, wkh, wvh, woh);
    proj_qkv<<<dim3(B * 16, 8, 3), blk, 0, stream>>>(
        xTq, xTk, xTv, wqh, wkh, wvh, bq, bk, bv, qh, kh, vh);
    attn_mfma<<<dim3(T_LEN / 64, NH, B), blk, 0, stream>>>(qh, kh, vh, erk, erv, ch);
    proj_out<<<dim3(B * 16, 8), blk, 0, stream>>>(ch, woh, bo, (float*)d_out);
}

// Round 3
// 166.430 us; speedup vs baseline: 2.5784x; 1.0296x over previous
//
#include <hip/hip_runtime.h>

#define T_LEN 1024
#define NH 8
#define DH 64
#define CCH 512
#define LOG2E 1.44269504088896340736f

typedef _Float16 f16;
typedef _Float16 f16x8 __attribute__((ext_vector_type(8)));
typedef _Float16 f16x4 __attribute__((ext_vector_type(4)));
typedef float f32x4 __attribute__((ext_vector_type(4)));

// async global->LDS DMA, 16B per lane. LDS dest must equal wave-uniform base + lane*16.
__device__ __forceinline__ void dma16(const void* g, void* l)
{
    __builtin_amdgcn_global_load_lds((const __attribute__((address_space(1))) void*)g,
                                     (__attribute__((address_space(3))) void*)l, 16, 0, 0);
}

// ---------------------------------------------------------------------------
// prep: fused [transpose+cvt x -> xT fp16 [b*t][c]] and [W fp32 -> fp16].
// grid(16, 8, 3B + 8), block 256.
// ---------------------------------------------------------------------------
__global__ __launch_bounds__(256)
void prep_kernel(const float* __restrict__ x0, const float* __restrict__ x1,
                 const float* __restrict__ x2, const float* __restrict__ W0,
                 const float* __restrict__ W1, const float* __restrict__ W2,
                 const float* __restrict__ W3, f16* __restrict__ o0,
                 f16* __restrict__ o1, f16* __restrict__ o2, f16* __restrict__ w0,
                 f16* __restrict__ w1, f16* __restrict__ w2, f16* __restrict__ w3,
                 int B)
{
    const int z = blockIdx.z;
    if (z < 3 * B) {
        const int t0 = blockIdx.x * 64, c0 = blockIdx.y * 64;
        const int which = z / B, b = z % B;
        const float* x = (which == 0) ? x0 : (which == 1) ? x1 : x2;
        f16* o = (which == 0) ? o0 : (which == 1) ? o1 : o2;

        __shared__ float L[64 * 68];
        const int cl = threadIdx.x & 63, g = threadIdx.x >> 6;
        const float* src = x + ((size_t)(b * CCH + c0 + cl)) * T_LEN + t0 + g * 16;
        #pragma unroll
        for (int j = 0; j < 4; ++j)
            *(float4*)&L[cl * 68 + g * 16 + 4 * j] = *(const float4*)&src[4 * j];
        __syncthreads();
        const int tl = threadIdx.x & 63, cg = (threadIdx.x >> 6) * 16;
        f16 h[16];
        #pragma unroll
        for (int j = 0; j < 16; ++j) h[j] = (f16)L[(cg + j) * 68 + tl];
        f16* dst = o + ((size_t)(b * T_LEN + t0 + tl)) * CCH + c0 + cg;
        *(f16x8*)&dst[0] = *(f16x8*)&h[0];
        *(f16x8*)&dst[8] = *(f16x8*)&h[8];
    } else {
        const int slice = z - 3 * B;
        size_t i = ((size_t)(slice * 128 + blockIdx.y * 16 + blockIdx.x) * 256 + threadIdx.x) * 4;
        const int wi = (int)(i >> 18);
        const size_t off = i & 262143;
        const float* src = (wi == 0) ? W0 : (wi == 1) ? W1 : (wi == 2) ? W2 : W3;
        f16* dst = (wi == 0) ? w0 : (wi == 1) ? w1 : (wi == 2) ? w2 : w3;
        float4 v4 = *(const float4*)&src[off];
        f16x4 h = {(f16)v4.x, (f16)v4.y, (f16)v4.z, (f16)v4.w};
        *(f16x4*)&dst[off] = h;
    }
}

// ---------------------------------------------------------------------------
// Fused q/k/v projections, fp16 MFMA (unchanged from round 2).
// ---------------------------------------------------------------------------
__global__ __launch_bounds__(256)
void proj_qkv(const f16* __restrict__ xq, const f16* __restrict__ xk,
              const f16* __restrict__ xv, const f16* __restrict__ wq,
              const f16* __restrict__ wk, const f16* __restrict__ wv,
              const float* __restrict__ bq, const float* __restrict__ bk,
              const float* __restrict__ bv, f16* __restrict__ qo,
              f16* __restrict__ ko, f16* __restrict__ vo)
{
    const int which = blockIdx.z;
    const f16* X = (which == 0) ? xq : (which == 1) ? xk : xv;
    const f16* W = (which == 0) ? wq : (which == 1) ? wk : wv;
    const float* bias = (which == 0) ? bq : (which == 1) ? bk : bv;
    const float scale = (which == 0) ? 0.125f * LOG2E : 1.0f;

    const int r0 = blockIdx.x * 64;
    const int o0 = blockIdx.y * 64;
    const int tid = threadIdx.x;
    const int w = tid >> 6, quad = (tid >> 4) & 3, l15 = tid & 15;

    __shared__ f16 Xs[64 * 72], Ws[64 * 72];
    f32x4 acc[4] = {};

    for (int c0 = 0; c0 < CCH; c0 += 64) {
        if (c0) __syncthreads();
        #pragma unroll
        for (int j = 0; j < 2; ++j) {
            int cid = tid + 256 * j;
            int row = cid >> 3, c8 = (cid & 7) * 8;
            *(f16x8*)&Xs[row * 72 + c8] = *(const f16x8*)&X[(size_t)(r0 + row) * CCH + c0 + c8];
            *(f16x8*)&Ws[row * 72 + c8] = *(const f16x8*)&W[(size_t)(o0 + row) * CCH + c0 + c8];
        }
        __syncthreads();
        const f16* Ab = (which < 2) ? Xs : Ws;
        const f16* Bb = (which < 2) ? Ws : Xs;
        #pragma unroll
        for (int ks = 0; ks < 2; ++ks) {
            f16x8 a = *(const f16x8*)&Ab[(16 * w + l15) * 72 + ks * 32 + quad * 8];
            #pragma unroll
            for (int ct = 0; ct < 4; ++ct) {
                f16x8 bf = *(const f16x8*)&Bb[(16 * ct + l15) * 72 + ks * 32 + quad * 8];
                acc[ct] = __builtin_amdgcn_mfma_f32_16x16x32_f16(a, bf, acc[ct], 0, 0, 0);
            }
        }
    }

    if (which < 2) {
        f16* out = (which == 0) ? qo : ko;
        #pragma unroll
        for (int ct = 0; ct < 4; ++ct) {
            int col = o0 + 16 * ct + l15;
            float bvl = bias[col];
            #pragma unroll
            for (int r = 0; r < 4; ++r) {
                int row = r0 + 16 * w + quad * 4 + r;
                out[(size_t)row * CCH + col] = (f16)((acc[ct][r] + bvl) * scale);
            }
        }
    } else {
        const int bb = r0 >> 10, tb = r0 & 1023;
        #pragma unroll
        for (int r = 0; r < 4; ++r) {
            int row_o = o0 + 16 * w + quad * 4 + r;
            float bvl = bias[row_o];
            #pragma unroll
            for (int ct = 0; ct < 4; ++ct)
                vo[((size_t)(bb * CCH + row_o)) * T_LEN + tb + 16 * ct + l15] =
                    (f16)(acc[ct][r] + bvl);
        }
    }
}

// ---------------------------------------------------------------------------
// MFMA flash attention, split-K (2 splits), no-max softmax, S^T orientation,
// XOR-swizzled LDS, global_load_lds staging. grid(16, NH, 2B), block 256.
// Writes unnormalized O partial (f16) + row-sum l (f32) per split.
// ---------------------------------------------------------------------------
__global__ __launch_bounds__(256)
void attn_mfma(const f16* __restrict__ q, const f16* __restrict__ kk,
               const f16* __restrict__ v, const float* __restrict__ ekg,
               const float* __restrict__ evg, f16* __restrict__ Op0,
               f16* __restrict__ Op1, float* __restrict__ l0,
               float* __restrict__ l1)
{
    const int t0 = blockIdx.x * 64, h = blockIdx.y;
    const int b = blockIdx.z >> 1, split = blockIdx.z & 1;
    const int tid = threadIdx.x;
    const int w = tid >> 6, lane = tid & 63;
    const int quad = lane >> 4, l15 = lane & 15;

    f16* Op = split ? Op1 : Op0;
    float* lbuf = split ? l1 : l0;

    __shared__ __align__(16) f16 Qs[4096], Ks[4096], Vs[4096], Ps[4096];
    __shared__ float eks[576], evs[576];

    // swizzled staging pattern: row = (tid>>3)+32j, stored slot (tid&7) holds
    // global column slot ((tid&7) ^ (row&7)). row&7 invariant under j.
    const int srow = tid >> 3;
    const int scol = ((tid & 7) ^ (srow & 7)) << 3;

    for (int i = tid; i < 576; i += 256) {
        eks[i] = ekg[h * 576 + i];
        evs[i] = evg[h * 576 + i];
    }

    // Q tile DMA
    dma16(q + ((size_t)(b * T_LEN + t0 + srow)) * CCH + h * DH + scol, &Qs[(size_t)tid * 8]);
    dma16(q + ((size_t)(b * T_LEN + t0 + srow + 32)) * CCH + h * DH + scol, &Qs[((size_t)tid + 256) * 8]);
    __syncthreads();

    // Q B-fragments held in registers for the whole kernel
    f16x8 qf[2];
    #pragma unroll
    for (int ks = 0; ks < 2; ++ks)
        qf[ks] = *(const f16x8*)&Qs[(16 * w + l15) * 64 + (((ks * 4 + quad) ^ (l15 & 7)) << 3)];

    const int kb0 = split * 8;
    const f16* gk = kk + ((size_t)(b * T_LEN + kb0 * 64 + srow)) * CCH + h * DH + scol;
    const f16* gv = v + ((size_t)(b * CCH + h * DH + srow)) * T_LEN + kb0 * 64 + scol;

    const int myt = 16 * w + l15;   // this lane's t-column (S^T layout)
    float Ssum = 0.f;
    f32x4 O[4] = {};

    const bool corner_hi = (blockIdx.x == 0) && (split == 1);
    const bool corner_lo = (blockIdx.x == 15) && (split == 0);

    for (int kb = kb0; kb < kb0 + 8; ++kb) {
        __syncthreads();   // prior tile's PV/rel-V reads done
        dma16(gk, &Ks[(size_t)tid * 8]);
        dma16(gk + (size_t)32 * CCH, &Ks[((size_t)tid + 256) * 8]);
        dma16(gv, &Vs[(size_t)tid * 8]);
        dma16(gv + (size_t)32 * T_LEN, &Vs[((size_t)tid + 256) * 8]);
        gk += (size_t)64 * CCH;
        gv += 64;
        __syncthreads();   // vmcnt(0) drained here -> tiles visible

        // ----- S^T = K Q^T : D[s][t], lane col = t = 16w+l15, rows s = 16ct+4quad+r
        f32x4 S[4] = {};
        #pragma unroll
        for (int ks = 0; ks < 2; ++ks) {
            #pragma unroll
            for (int ct = 0; ct < 4; ++ct) {
                f16x8 a = *(const f16x8*)&Ks[(16 * ct + l15) * 64 + (((ks * 4 + quad) ^ (l15 & 7)) << 3)];
                S[ct] = __builtin_amdgcn_mfma_f32_16x16x32_f16(a, qf[ks], S[ct], 0, 0, 0);
            }
        }

        // ----- corner relative-K bias (rare)
        if ((corner_hi && kb == 15) || (corner_lo && kb == 0)) {
            const int s0g = kb * 64;
            #pragma unroll
            for (int ct = 0; ct < 4; ++ct)
                #pragma unroll
                for (int r = 0; r < 4; ++r) {
                    int t_g = t0 + myt;
                    int s_g = s0g + 16 * ct + 4 * quad + r;
                    int df = s_g - t_g;
                    if (df >= 1019 && df <= 1023) {
                        const float* ekp = &eks[(df - 1019) * 64];
                        float sacc = 0.f;
                        for (int d = 0; d < 64; ++d)
                            sacc += (float)Qs[myt * 64 + (((d >> 3) ^ (myt & 7)) << 3) + (d & 7)] * ekp[d];
                        S[ct][r] += sacc;
                    } else if (df >= -1023 && df <= -1021) {
                        const float* ekp = &eks[(1029 + df) * 64];
                        const int t2 = myt - 1;   // t>=1021 -> myt>=61, safe
                        float sacc = 0.f;
                        for (int d = 0; d < 64; ++d)
                            sacc += (float)Qs[t2 * 64 + (((d >> 3) ^ (t2 & 7)) << 3) + (d & 7)] * ekp[d];
                        S[ct][r] += sacc;
                    }
                }
        }

        // ----- no-max softmax: P = exp2(S), accumulate l, vectorized P store
        #pragma unroll
        for (int ct = 0; ct < 4; ++ct) {
            f16x4 pk_;
            #pragma unroll
            for (int r = 0; r < 4; ++r) {
                float p = exp2f(S[ct][r]);
                Ssum += p;
                pk_[r] = (f16)p;
            }
            int colh = (((2 * ct + (quad >> 1)) ^ (myt & 7)) << 3) + (quad & 1) * 4;
            *(f16x4*)&Ps[myt * 64 + colh] = pk_;
        }
        __syncthreads();   // Ps ready

        // ----- O += P V : D[t][d], rows t = 16w+4quad+r, cols d = 16ct+l15
        #pragma unroll
        for (int ks = 0; ks < 2; ++ks) {
            f16x8 a = *(const f16x8*)&Ps[(16 * w + l15) * 64 + (((ks * 4 + quad) ^ (l15 & 7)) << 3)];
            #pragma unroll
            for (int ct = 0; ct < 4; ++ct) {
                f16x8 bf = *(const f16x8*)&Vs[(16 * ct + l15) * 64 + (((ks * 4 + quad) ^ (l15 & 7)) << 3)];
                O[ct] = __builtin_amdgcn_mfma_f32_16x16x32_f16(a, bf, O[ct], 0, 0, 0);
            }
        }

        // ----- windowed relative-V (only tiles near the diagonal)
        const int s0g = kb * 64;
        if (s0g <= t0 + 67 && s0g + 63 >= t0 - 4) {
            #pragma unroll
            for (int r = 0; r < 4; ++r) {
                int t_loc = 16 * w + 4 * quad + r;
                int t_g = t0 + t_loc;
                int slo = max(s0g, t_g - 4), shi = min(s0g + 63, t_g + 4);
                for (int s = slo; s <= shi; ++s) {
                    int sl = s - s0g;
                    float p = (float)Ps[t_loc * 64 + (((sl >> 3) ^ (t_loc & 7)) << 3) + (sl & 7)];
                    const float* evp = &evs[(s - t_g + 4) * 64];
                    #pragma unroll
                    for (int ct = 0; ct < 4; ++ct)
                        O[ct][r] += p * evp[16 * ct + l15];
                }
            }
        }
    }

    // final l reduction across quads (lanes sharing l15)
    Ssum += __shfl_xor(Ssum, 16);
    Ssum += __shfl_xor(Ssum, 32);
    if (quad == 0)
        lbuf[((size_t)b * NH + h) * T_LEN + t0 + myt] = Ssum;

    // unnormalized O partial, f16
    #pragma unroll
    for (int r = 0; r < 4; ++r) {
        int t_g = t0 + 16 * w + 4 * quad + r;
        size_t rowo = ((size_t)(b * T_LEN + t_g)) * CCH + h * DH;
        #pragma unroll
        for (int ct = 0; ct < 4; ++ct)
            Op[rowo + 16 * ct + l15] = (f16)O[ct][r];
    }
}

// ---------------------------------------------------------------------------
// Output projection with fused split-combine: ctx = (Op0+Op1)/(l0+l1),
// out[b][o][t] fp32 = Wo*ctx + bo. grid(B*16, 8), block 256.
// ---------------------------------------------------------------------------
__global__ __launch_bounds__(256)
void proj_out(const f16* __restrict__ Op0, const f16* __restrict__ Op1,
              const float* __restrict__ l0, const float* __restrict__ l1,
              const f16* __restrict__ Wo, const float* __restrict__ bo,
              float* __restrict__ out)
{
    const int r0 = blockIdx.x * 64;
    const int o0 = blockIdx.y * 64;
    const int tid = threadIdx.x;
    const int w = tid >> 6, quad = (tid >> 4) & 3, l15 = tid & 15;

    __shared__ f16 Xs[64 * 72], Ws[64 * 72];
    f32x4 acc[4] = {};

    for (int c0 = 0; c0 < CCH; c0 += 64) {
        if (c0) __syncthreads();
        #pragma unroll
        for (int j = 0; j < 2; ++j) {
            int cid = tid + 256 * j;
            int rw = cid >> 3, cc = (cid & 7) * 8;
            int gr = r0 + rw;
            int bb = gr >> 10, tt = gr & 1023;
            int hh = (c0 + cc) >> 6;
            size_t li = ((size_t)bb * NH + hh) * T_LEN + tt;
            float rl = 1.0f / (l0[li] + l1[li]);
            f16x8 a0 = *(const f16x8*)&Op0[(size_t)gr * CCH + c0 + cc];
            f16x8 a1 = *(const f16x8*)&Op1[(size_t)gr * CCH + c0 + cc];
            f16 hx[8];
            #pragma unroll
            for (int e = 0; e < 8; ++e)
                hx[e] = (f16)(((float)a0[e] + (float)a1[e]) * rl);
            *(f16x8*)&Xs[rw * 72 + cc] = *(f16x8*)hx;
            *(f16x8*)&Ws[rw * 72 + cc] = *(const f16x8*)&Wo[(size_t)(o0 + rw) * CCH + c0 + cc];
        }
        __syncthreads();
        #pragma unroll
        for (int ks = 0; ks < 2; ++ks) {
            f16x8 a = *(const f16x8*)&Ws[(16 * w + l15) * 72 + ks * 32 + quad * 8];
            #pragma unroll
            for (int ct = 0; ct < 4; ++ct) {
                f16x8 bf = *(const f16x8*)&Xs[(16 * ct + l15) * 72 + ks * 32 + quad * 8];
                acc[ct] = __builtin_amdgcn_mfma_f32_16x16x32_f16(a, bf, acc[ct], 0, 0, 0);
            }
        }
    }

    const int bb = r0 >> 10, tb = r0 & 1023;
    #pragma unroll
    for (int r = 0; r < 4; ++r) {
        int row_o = o0 + 16 * w + quad * 4 + r;
        float bvl = bo[row_o];
        #pragma unroll
        for (int ct = 0; ct < 4; ++ct)
            out[((size_t)(bb * CCH + row_o)) * T_LEN + tb + 16 * ct + l15] =
                acc[ct][r] + bvl;
    }
}

// ---------------------------------------------------------------------------
extern "C" void kernel_launch(void* const* d_in, const int* in_sizes, int n_in,
                              void* d_out, int out_size, void* d_ws, size_t ws_size,
                              hipStream_t stream)
{
    const float* x_q = (const float*)d_in[0];
    const float* x_k = (const float*)d_in[1];
    const float* x_v = (const float*)d_in[2];
    const float* Wq  = (const float*)d_in[3];
    const float* bq  = (const float*)d_in[4];
    const float* Wk  = (const float*)d_in[5];
    const float* bk  = (const float*)d_in[6];
    const float* Wv  = (const float*)d_in[7];
    const float* bv  = (const float*)d_in[8];
    const float* Wo  = (const float*)d_in[9];
    const float* bo  = (const float*)d_in[10];
    const float* erk = (const float*)d_in[11];
    const float* erv = (const float*)d_in[12];

    const int B = in_sizes[0] / (CCH * T_LEN);
    const size_t te = (size_t)B * CCH * T_LEN;
    const size_t we = (size_t)CCH * CCH;

    f16* p = (f16*)d_ws;
    f16* xTq = p; p += te;
    f16* xTk = p; p += te;
    f16* xTv = p; p += te;
    f16* wqh = p; p += we;
    f16* wkh = p; p += we;
    f16* wvh = p; p += we;
    f16* woh = p; p += we;
    f16* qh  = p; p += te;
    f16* kh  = p; p += te;
    f16* vh  = p; p += te;

    // aliases: xT* are dead after proj_qkv; reuse for attention partials
    f16* Op0 = xTq;
    f16* Op1 = xTk;
    float* l0 = (float*)xTv;
    float* l1 = l0 + (size_t)B * NH * T_LEN;

    dim3 blk(256);
    prep_kernel<<<dim3(16, 8, 3 * B + 8), blk, 0, stream>>>(
        x_q, x_k, x_v, Wq, Wk, Wv, Wo, xTq, xTk, xTv, wqh, wkh, wvh, woh, B);
    proj_qkv<<<dim3(B * 16, 8, 3), blk, 0, stream>>>(
        xTq, xTk, xTv, wqh, wkh, wvh, bq, bk, bv, qh, kh, vh);
    attn_mfma<<<dim3(T_LEN / 64, NH, 2 * B), blk, 0, stream>>>(
        qh, kh, vh, erk, erv, Op0, Op1, l0, l1);
    proj_out<<<dim3(B * 16, 8), blk, 0, stream>>>(
        Op0, Op1, l0, l1, woh, bo, (float*)d_out);
}

// Round 4
// 159.783 us; speedup vs baseline: 2.6856x; 1.0416x over previous
//
#include <hip/hip_runtime.h>

#define T_LEN 1024
#define NH 8
#define DH 64
#define CCH 512
#define LOG2E 1.44269504088896340736f

typedef _Float16 f16;
typedef _Float16 f16x8 __attribute__((ext_vector_type(8)));
typedef _Float16 f16x4 __attribute__((ext_vector_type(4)));
typedef float f32x4 __attribute__((ext_vector_type(4)));

// async global->LDS DMA, 16B per lane. LDS dest must equal wave-uniform base + lane*16.
__device__ __forceinline__ void dma16(const void* g, void* l)
{
    __builtin_amdgcn_global_load_lds((const __attribute__((address_space(1))) void*)g,
                                     (__attribute__((address_space(3))) void*)l, 16, 0, 0);
}

// ---------------------------------------------------------------------------
// prep: fused [transpose+cvt x -> xT fp16 [b*t][c]] and [W fp32 -> fp16].
// grid(16, 8, 3B + 8), block 256.
// ---------------------------------------------------------------------------
__global__ __launch_bounds__(256)
void prep_kernel(const float* __restrict__ x0, const float* __restrict__ x1,
                 const float* __restrict__ x2, const float* __restrict__ W0,
                 const float* __restrict__ W1, const float* __restrict__ W2,
                 const float* __restrict__ W3, f16* __restrict__ o0,
                 f16* __restrict__ o1, f16* __restrict__ o2, f16* __restrict__ w0,
                 f16* __restrict__ w1, f16* __restrict__ w2, f16* __restrict__ w3,
                 int B)
{
    const int z = blockIdx.z;
    if (z < 3 * B) {
        const int t0 = blockIdx.x * 64, c0 = blockIdx.y * 64;
        const int which = z / B, b = z % B;
        const float* x = (which == 0) ? x0 : (which == 1) ? x1 : x2;
        f16* o = (which == 0) ? o0 : (which == 1) ? o1 : o2;

        __shared__ float L[64 * 68];
        const int cl = threadIdx.x & 63, g = threadIdx.x >> 6;
        const float* src = x + ((size_t)(b * CCH + c0 + cl)) * T_LEN + t0 + g * 16;
        #pragma unroll
        for (int j = 0; j < 4; ++j)
            *(float4*)&L[cl * 68 + g * 16 + 4 * j] = *(const float4*)&src[4 * j];
        __syncthreads();
        const int tl = threadIdx.x & 63, cg = (threadIdx.x >> 6) * 16;
        f16 h[16];
        #pragma unroll
        for (int j = 0; j < 16; ++j) h[j] = (f16)L[(cg + j) * 68 + tl];
        f16* dst = o + ((size_t)(b * T_LEN + t0 + tl)) * CCH + c0 + cg;
        *(f16x8*)&dst[0] = *(f16x8*)&h[0];
        *(f16x8*)&dst[8] = *(f16x8*)&h[8];
    } else {
        const int slice = z - 3 * B;
        size_t i = ((size_t)(slice * 128 + blockIdx.y * 16 + blockIdx.x) * 256 + threadIdx.x) * 4;
        const int wi = (int)(i >> 18);
        const size_t off = i & 262143;
        const float* src = (wi == 0) ? W0 : (wi == 1) ? W1 : (wi == 2) ? W2 : W3;
        f16* dst = (wi == 0) ? w0 : (wi == 1) ? w1 : (wi == 2) ? w2 : w3;
        float4 v4 = *(const float4*)&src[off];
        f16x4 h = {(f16)v4.x, (f16)v4.y, (f16)v4.z, (f16)v4.w};
        *(f16x4*)&dst[off] = h;
    }
}

// ---------------------------------------------------------------------------
// Fused q/k/v projections, m97-style: 128(t)x64(o) tile, BK=64, double-buffered
// global_load_lds staging, XOR-swizzled LDS. grid(B*8, 8, 3), block 256.
// which=0,1 (q,k): D[m=t][n=o] -> store [b*t][c] f16 (q scaled 0.125*log2e)
// which=2   (v):   D[m=o][n=t] -> store [b][c][t] f16
// ---------------------------------------------------------------------------
__global__ __launch_bounds__(256)
void proj_qkv(const f16* __restrict__ xq, const f16* __restrict__ xk,
              const f16* __restrict__ xv, const f16* __restrict__ wq,
              const f16* __restrict__ wk, const f16* __restrict__ wv,
              const float* __restrict__ bq, const float* __restrict__ bk,
              const float* __restrict__ bv, f16* __restrict__ qo,
              f16* __restrict__ ko, f16* __restrict__ vo)
{
    const int which = blockIdx.z;
    const f16* X = (which == 0) ? xq : (which == 1) ? xk : xv;
    const f16* W = (which == 0) ? wq : (which == 1) ? wk : wv;
    const float* bias = (which == 0) ? bq : (which == 1) ? bk : bv;
    const float scale = (which == 0) ? 0.125f * LOG2E : 1.0f;

    const int r0 = blockIdx.x * 128;   // flat (b,t) row base
    const int o0 = blockIdx.y * 64;    // out-channel base
    const int tid = threadIdx.x;
    const int w = tid >> 6, lane = tid & 63;
    const int quad = lane >> 4, l15 = lane & 15;

    __shared__ __align__(16) f16 Xs[2][128 * 64];
    __shared__ __align__(16) f16 Ws[2][64 * 64];

    const int srow = tid >> 3;                     // 0..31
    const int scol = ((tid & 7) ^ (srow & 7)) << 3;

    const f16* Xg = X + (size_t)(r0 + srow) * CCH + scol;
    const f16* Wg = W + (size_t)(o0 + srow) * CCH + scol;

    // prologue: stage c-chunk 0 into buffer 0
    #pragma unroll
    for (int j = 0; j < 4; ++j)
        dma16(Xg + (size_t)(32 * j) * CCH, &Xs[0][(size_t)tid * 8 + j * 2048]);
    #pragma unroll
    for (int j = 0; j < 2; ++j)
        dma16(Wg + (size_t)(32 * j) * CCH, &Ws[0][(size_t)tid * 8 + j * 2048]);

    f32x4 acc[8] = {};

    for (int kc = 0; kc < 8; ++kc) {
        __syncthreads();   // drains DMA for chunk kc; guards buffer reuse
        if (kc < 7) {
            const int bf = (kc + 1) & 1, c1 = (kc + 1) * 64;
            #pragma unroll
            for (int j = 0; j < 4; ++j)
                dma16(Xg + c1 + (size_t)(32 * j) * CCH, &Xs[bf][(size_t)tid * 8 + j * 2048]);
            #pragma unroll
            for (int j = 0; j < 2; ++j)
                dma16(Wg + c1 + (size_t)(32 * j) * CCH, &Ws[bf][(size_t)tid * 8 + j * 2048]);
        }
        const int cb = kc & 1;
        #pragma unroll
        for (int ks = 0; ks < 2; ++ks) {
            const int sl = ((ks * 4 + quad) ^ (l15 & 7)) << 3;
            f16x8 xf[2], wf[4];
            #pragma unroll
            for (int im = 0; im < 2; ++im)
                xf[im] = *(const f16x8*)&Xs[cb][(32 * w + 16 * im + l15) * 64 + sl];
            #pragma unroll
            for (int cm = 0; cm < 4; ++cm)
                wf[cm] = *(const f16x8*)&Ws[cb][(16 * cm + l15) * 64 + sl];
            if (which < 2) {
                #pragma unroll
                for (int im = 0; im < 2; ++im)
                    #pragma unroll
                    for (int cm = 0; cm < 4; ++cm)
                        acc[im * 4 + cm] = __builtin_amdgcn_mfma_f32_16x16x32_f16(
                            xf[im], wf[cm], acc[im * 4 + cm], 0, 0, 0);
            } else {
                #pragma unroll
                for (int cm = 0; cm < 4; ++cm)
                    #pragma unroll
                    for (int in = 0; in < 2; ++in)
                        acc[cm * 2 + in] = __builtin_amdgcn_mfma_f32_16x16x32_f16(
                            wf[cm], xf[in], acc[cm * 2 + in], 0, 0, 0);
            }
        }
    }

    if (which < 2) {
        f16* out = (which == 0) ? qo : ko;
        float bl[4];
        #pragma unroll
        for (int cm = 0; cm < 4; ++cm) bl[cm] = bias[o0 + 16 * cm + l15];
        #pragma unroll
        for (int im = 0; im < 2; ++im)
            #pragma unroll
            for (int r = 0; r < 4; ++r) {
                size_t row = (size_t)(r0 + 32 * w + 16 * im + 4 * quad + r) * CCH;
                #pragma unroll
                for (int cm = 0; cm < 4; ++cm)
                    out[row + o0 + 16 * cm + l15] =
                        (f16)((acc[im * 4 + cm][r] + bl[cm]) * scale);
            }
    } else {
        const int bb = r0 >> 10, tb = r0 & 1023;
        #pragma unroll
        for (int cm = 0; cm < 4; ++cm) {
            float4 bv4 = *(const float4*)&bias[o0 + 16 * cm + 4 * quad];
            float bl[4] = {bv4.x, bv4.y, bv4.z, bv4.w};
            #pragma unroll
            for (int r = 0; r < 4; ++r) {
                size_t row = ((size_t)(bb * CCH + o0 + 16 * cm + 4 * quad + r)) * T_LEN;
                #pragma unroll
                for (int in = 0; in < 2; ++in)
                    vo[row + tb + 32 * w + 16 * in + l15] =
                        (f16)(acc[cm * 2 + in][r] + bl[r]);
            }
        }
    }
}

// ---------------------------------------------------------------------------
// MFMA flash attention, split-K (2 splits), no-max softmax, S^T orientation,
// XOR-swizzled LDS, global_load_lds staging. grid(16, NH, 2B), block 256.
// (unchanged from round 3)
// ---------------------------------------------------------------------------
__global__ __launch_bounds__(256)
void attn_mfma(const f16* __restrict__ q, const f16* __restrict__ kk,
               const f16* __restrict__ v, const float* __restrict__ ekg,
               const float* __restrict__ evg, f16* __restrict__ Op0,
               f16* __restrict__ Op1, float* __restrict__ l0,
               float* __restrict__ l1)
{
    const int t0 = blockIdx.x * 64, h = blockIdx.y;
    const int b = blockIdx.z >> 1, split = blockIdx.z & 1;
    const int tid = threadIdx.x;
    const int w = tid >> 6, lane = tid & 63;
    const int quad = lane >> 4, l15 = lane & 15;

    f16* Op = split ? Op1 : Op0;
    float* lbuf = split ? l1 : l0;

    __shared__ __align__(16) f16 Qs[4096], Ks[4096], Vs[4096], Ps[4096];
    __shared__ float eks[576], evs[576];

    const int srow = tid >> 3;
    const int scol = ((tid & 7) ^ (srow & 7)) << 3;

    for (int i = tid; i < 576; i += 256) {
        eks[i] = ekg[h * 576 + i];
        evs[i] = evg[h * 576 + i];
    }

    dma16(q + ((size_t)(b * T_LEN + t0 + srow)) * CCH + h * DH + scol, &Qs[(size_t)tid * 8]);
    dma16(q + ((size_t)(b * T_LEN + t0 + srow + 32)) * CCH + h * DH + scol, &Qs[((size_t)tid + 256) * 8]);
    __syncthreads();

    f16x8 qf[2];
    #pragma unroll
    for (int ks = 0; ks < 2; ++ks)
        qf[ks] = *(const f16x8*)&Qs[(16 * w + l15) * 64 + (((ks * 4 + quad) ^ (l15 & 7)) << 3)];

    const int kb0 = split * 8;
    const f16* gk = kk + ((size_t)(b * T_LEN + kb0 * 64 + srow)) * CCH + h * DH + scol;
    const f16* gv = v + ((size_t)(b * CCH + h * DH + srow)) * T_LEN + kb0 * 64 + scol;

    const int myt = 16 * w + l15;
    float Ssum = 0.f;
    f32x4 O[4] = {};

    const bool corner_hi = (blockIdx.x == 0) && (split == 1);
    const bool corner_lo = (blockIdx.x == 15) && (split == 0);

    for (int kb = kb0; kb < kb0 + 8; ++kb) {
        __syncthreads();
        dma16(gk, &Ks[(size_t)tid * 8]);
        dma16(gk + (size_t)32 * CCH, &Ks[((size_t)tid + 256) * 8]);
        dma16(gv, &Vs[(size_t)tid * 8]);
        dma16(gv + (size_t)32 * T_LEN, &Vs[((size_t)tid + 256) * 8]);
        gk += (size_t)64 * CCH;
        gv += 64;
        __syncthreads();

        f32x4 S[4] = {};
        #pragma unroll
        for (int ks = 0; ks < 2; ++ks) {
            #pragma unroll
            for (int ct = 0; ct < 4; ++ct) {
                f16x8 a = *(const f16x8*)&Ks[(16 * ct + l15) * 64 + (((ks * 4 + quad) ^ (l15 & 7)) << 3)];
                S[ct] = __builtin_amdgcn_mfma_f32_16x16x32_f16(a, qf[ks], S[ct], 0, 0, 0);
            }
        }

        if ((corner_hi && kb == 15) || (corner_lo && kb == 0)) {
            const int s0g = kb * 64;
            #pragma unroll
            for (int ct = 0; ct < 4; ++ct)
                #pragma unroll
                for (int r = 0; r < 4; ++r) {
                    int t_g = t0 + myt;
                    int s_g = s0g + 16 * ct + 4 * quad + r;
                    int df = s_g - t_g;
                    if (df >= 1019 && df <= 1023) {
                        const float* ekp = &eks[(df - 1019) * 64];
                        float sacc = 0.f;
                        for (int d = 0; d < 64; ++d)
                            sacc += (float)Qs[myt * 64 + (((d >> 3) ^ (myt & 7)) << 3) + (d & 7)] * ekp[d];
                        S[ct][r] += sacc;
                    } else if (df >= -1023 && df <= -1021) {
                        const float* ekp = &eks[(1029 + df) * 64];
                        const int t2 = myt - 1;
                        float sacc = 0.f;
                        for (int d = 0; d < 64; ++d)
                            sacc += (float)Qs[t2 * 64 + (((d >> 3) ^ (t2 & 7)) << 3) + (d & 7)] * ekp[d];
                        S[ct][r] += sacc;
                    }
                }
        }

        #pragma unroll
        for (int ct = 0; ct < 4; ++ct) {
            f16x4 pk_;
            #pragma unroll
            for (int r = 0; r < 4; ++r) {
                float p = exp2f(S[ct][r]);
                Ssum += p;
                pk_[r] = (f16)p;
            }
            int colh = (((2 * ct + (quad >> 1)) ^ (myt & 7)) << 3) + (quad & 1) * 4;
            *(f16x4*)&Ps[myt * 64 + colh] = pk_;
        }
        __syncthreads();

        #pragma unroll
        for (int ks = 0; ks < 2; ++ks) {
            f16x8 a = *(const f16x8*)&Ps[(16 * w + l15) * 64 + (((ks * 4 + quad) ^ (l15 & 7)) << 3)];
            #pragma unroll
            for (int ct = 0; ct < 4; ++ct) {
                f16x8 bf = *(const f16x8*)&Vs[(16 * ct + l15) * 64 + (((ks * 4 + quad) ^ (l15 & 7)) << 3)];
                O[ct] = __builtin_amdgcn_mfma_f32_16x16x32_f16(a, bf, O[ct], 0, 0, 0);
            }
        }

        const int s0g = kb * 64;
        if (s0g <= t0 + 67 && s0g + 63 >= t0 - 4) {
            #pragma unroll
            for (int r = 0; r < 4; ++r) {
                int t_loc = 16 * w + 4 * quad + r;
                int t_g = t0 + t_loc;
                int slo = max(s0g, t_g - 4), shi = min(s0g + 63, t_g + 4);
                for (int s = slo; s <= shi; ++s) {
                    int sl = s - s0g;
                    float p = (float)Ps[t_loc * 64 + (((sl >> 3) ^ (t_loc & 7)) << 3) + (sl & 7)];
                    const float* evp = &evs[(s - t_g + 4) * 64];
                    #pragma unroll
                    for (int ct = 0; ct < 4; ++ct)
                        O[ct][r] += p * evp[16 * ct + l15];
                }
            }
        }
    }

    Ssum += __shfl_xor(Ssum, 16);
    Ssum += __shfl_xor(Ssum, 32);
    if (quad == 0)
        lbuf[((size_t)b * NH + h) * T_LEN + t0 + myt] = Ssum;

    #pragma unroll
    for (int r = 0; r < 4; ++r) {
        int t_g = t0 + 16 * w + 4 * quad + r;
        size_t rowo = ((size_t)(b * T_LEN + t_g)) * CCH + h * DH;
        #pragma unroll
        for (int ct = 0; ct < 4; ++ct)
            Op[rowo + 16 * ct + l15] = (f16)O[ct][r];
    }
}

// ---------------------------------------------------------------------------
// Split-combine: ctx = (Op0+Op1)/(l0+l1), f16, memory-bound pass.
// grid(B*256), block 256, 8 elems/thread.
// ---------------------------------------------------------------------------
__global__ __launch_bounds__(256)
void combine_kernel(const f16* __restrict__ Op0, const f16* __restrict__ Op1,
                    const float* __restrict__ l0, const float* __restrict__ l1,
                    f16* __restrict__ ctx)
{
    const size_t i8 = ((size_t)blockIdx.x * 256 + threadIdx.x) * 8;
    const size_t gr = i8 >> 9;          // flat (b,t)
    const int h = (int)((i8 & 511) >> 6);
    const size_t li = ((gr >> 10) * NH + h) * T_LEN + (gr & 1023);
    const float rl = 1.0f / (l0[li] + l1[li]);
    f16x8 a0 = *(const f16x8*)&Op0[i8];
    f16x8 a1 = *(const f16x8*)&Op1[i8];
    f16 o[8];
    #pragma unroll
    for (int e = 0; e < 8; ++e)
        o[e] = (f16)(((float)a0[e] + (float)a1[e]) * rl);
    *(f16x8*)&ctx[i8] = *(f16x8*)o;
}

// ---------------------------------------------------------------------------
// Output projection, m97-style: D[m=o][n=t], A=Wo[o][c], B=ctx[t][c].
// 64(o)x128(t) tile, BK=64, double-buffered DMA, XOR swizzle.
// grid(B*8, 8), block 256. fp32 out [b][o][t].
// ---------------------------------------------------------------------------
__global__ __launch_bounds__(256)
void proj_out(const f16* __restrict__ ctx, const f16* __restrict__ Wo,
              const float* __restrict__ bo, float* __restrict__ out)
{
    const int r0 = blockIdx.x * 128;   // flat (b,t)
    const int o0 = blockIdx.y * 64;
    const int tid = threadIdx.x;
    const int w = tid >> 6, lane = tid & 63;
    const int quad = lane >> 4, l15 = lane & 15;

    __shared__ __align__(16) f16 Cs[2][128 * 64];
    __shared__ __align__(16) f16 Ws[2][64 * 64];

    const int srow = tid >> 3;
    const int scol = ((tid & 7) ^ (srow & 7)) << 3;

    const f16* Cg = ctx + (size_t)(r0 + srow) * CCH + scol;
    const f16* Wg = Wo + (size_t)(o0 + srow) * CCH + scol;

    #pragma unroll
    for (int j = 0; j < 4; ++j)
        dma16(Cg + (size_t)(32 * j) * CCH, &Cs[0][(size_t)tid * 8 + j * 2048]);
    #pragma unroll
    for (int j = 0; j < 2; ++j)
        dma16(Wg + (size_t)(32 * j) * CCH, &Ws[0][(size_t)tid * 8 + j * 2048]);

    f32x4 acc[8] = {};

    for (int kc = 0; kc < 8; ++kc) {
        __syncthreads();
        if (kc < 7) {
            const int bf = (kc + 1) & 1, c1 = (kc + 1) * 64;
            #pragma unroll
            for (int j = 0; j < 4; ++j)
                dma16(Cg + c1 + (size_t)(32 * j) * CCH, &Cs[bf][(size_t)tid * 8 + j * 2048]);
            #pragma unroll
            for (int j = 0; j < 2; ++j)
                dma16(Wg + c1 + (size_t)(32 * j) * CCH, &Ws[bf][(size_t)tid * 8 + j * 2048]);
        }
        const int cb = kc & 1;
        #pragma unroll
        for (int ks = 0; ks < 2; ++ks) {
            const int sl = ((ks * 4 + quad) ^ (l15 & 7)) << 3;
            f16x8 cf[2], wf[4];
            #pragma unroll
            for (int in = 0; in < 2; ++in)
                cf[in] = *(const f16x8*)&Cs[cb][(32 * w + 16 * in + l15) * 64 + sl];
            #pragma unroll
            for (int cm = 0; cm < 4; ++cm)
                wf[cm] = *(const f16x8*)&Ws[cb][(16 * cm + l15) * 64 + sl];
            #pragma unroll
            for (int cm = 0; cm < 4; ++cm)
                #pragma unroll
                for (int in = 0; in < 2; ++in)
                    acc[cm * 2 + in] = __builtin_amdgcn_mfma_f32_16x16x32_f16(
                        wf[cm], cf[in], acc[cm * 2 + in], 0, 0, 0);
        }
    }

    const int bb = r0 >> 10, tb = r0 & 1023;
    #pragma unroll
    for (int cm = 0; cm < 4; ++cm) {
        float4 bv4 = *(const float4*)&bo[o0 + 16 * cm + 4 * quad];
        float bl[4] = {bv4.x, bv4.y, bv4.z, bv4.w};
        #pragma unroll
        for (int r = 0; r < 4; ++r) {
            size_t row = ((size_t)(bb * CCH + o0 + 16 * cm + 4 * quad + r)) * T_LEN;
            #pragma unroll
            for (int in = 0; in < 2; ++in)
                out[row + tb + 32 * w + 16 * in + l15] = acc[cm * 2 + in][r] + bl[r];
        }
    }
}

// ---------------------------------------------------------------------------
extern "C" void kernel_launch(void* const* d_in, const int* in_sizes, int n_in,
                              void* d_out, int out_size, void* d_ws, size_t ws_size,
                              hipStream_t stream)
{
    const float* x_q = (const float*)d_in[0];
    const float* x_k = (const float*)d_in[1];
    const float* x_v = (const float*)d_in[2];
    const float* Wq  = (const float*)d_in[3];
    const float* bq  = (const float*)d_in[4];
    const float* Wk  = (const float*)d_in[5];
    const float* bk  = (const float*)d_in[6];
    const float* Wv  = (const float*)d_in[7];
    const float* bv  = (const float*)d_in[8];
    const float* Wo  = (const float*)d_in[9];
    const float* bo  = (const float*)d_in[10];
    const float* erk = (const float*)d_in[11];
    const float* erv = (const float*)d_in[12];

    const int B = in_sizes[0] / (CCH * T_LEN);
    const size_t te = (size_t)B * CCH * T_LEN;
    const size_t we = (size_t)CCH * CCH;

    f16* p = (f16*)d_ws;
    f16* xTq = p; p += te;
    f16* xTk = p; p += te;
    f16* xTv = p; p += te;
    f16* wqh = p; p += we;
    f16* wkh = p; p += we;
    f16* wvh = p; p += we;
    f16* woh = p; p += we;
    f16* qh  = p; p += te;
    f16* kh  = p; p += te;
    f16* vh  = p; p += te;
    f16* Op0 = p; p += te;
    f16* Op1 = p; p += te;
    f16* ch  = p; p += te;
    float* l0 = (float*)p;
    float* l1 = l0 + (size_t)B * NH * T_LEN;

    dim3 blk(256);
    prep_kernel<<<dim3(16, 8, 3 * B + 8), blk, 0, stream>>>(
        x_q, x_k, x_v, Wq, Wk, Wv, Wo, xTq, xTk, xTv, wqh, wkh, wvh, woh, B);
    proj_qkv<<<dim3(B * 8, 8, 3), blk, 0, stream>>>(
        xTq, xTk, xTv, wqh, wkh, wvh, bq, bk, bv, qh, kh, vh);
    attn_mfma<<<dim3(T_LEN / 64, NH, 2 * B), blk, 0, stream>>>(
        qh, kh, vh, erk, erv, Op0, Op1, l0, l1);
    combine_kernel<<<dim3(B * 256), blk, 0, stream>>>(Op0, Op1, l0, l1, ch);
    proj_out<<<dim3(B * 8, 8), blk, 0, stream>>>(ch, woh, bo, (float*)d_out);
}